// Round 1
// 145.258 us; speedup vs baseline: 1.0436x; 1.0436x over previous
//
#include <hip/hip_runtime.h>
#include <stdint.h>

#define N_NODES 100000
#define N_EDGES 1600000
#define HIDDEN  64
#define SLOPE   0.01f
#define NBUCK   782      // ceil(N_NODES/128): coarse buckets of 128 dst nodes
#define CAPB    2816     // fixed slots per bucket (mean 2048, sd 45 -> 17 sigma)
#define PCHUNK  16384    // edges per partition block (98 blocks x 16 waves)
#define NPART   98       // ceil(N_EDGES/PCHUNK)
#define NSB     391      // scores blocks, 256 nodes each (391*256 = 100096)
#define NCAP    49       // LDS slots per node; ODD -> 392 B node stride de-aliases
                         // the 4 quarters' ds_read_b64 banks (48*8 aliased)

// ctrl layout: [0..NBUCK) bucket cursors; [NBUCK] init flag

// round-to-nearest-even fp32 -> bf16 (as ushort)
__device__ __forceinline__ unsigned short f2bf(float f) {
    uint32_t u = __float_as_uint(f);
    uint32_t r = u + 0x7FFFu + ((u >> 16) & 1u);
    return (unsigned short)(r >> 16);
}

// K1: fused build, 1024-thread blocks, ALL co-resident (489 blocks x 16
//     waves; 79 KB LDS -> 2 blocks/CU): build time ~ max(partition, scores).
//     Blocks [0, NPART): LDS-sort one 16384-edge chunk by bucket, reserve
//     once per (block,bucket), copy out as contiguous runs. Blocks
//     [NPART, NPART+NSB): scores + bf16 x copy, float4 per lane.
__global__ void __launch_bounds__(1024) k_build(const float* __restrict__ x,
                                                const float* __restrict__ w_i,
                                                const float* __restrict__ w_j,
                                                const int* __restrict__ srcs,
                                                const int* __restrict__ dsts,
                                                float* __restrict__ s_i,
                                                float* __restrict__ s_j,
                                                unsigned short* __restrict__ xb,
                                                int* __restrict__ ctrl,
                                                uint32_t* __restrict__ pairs) {
    __shared__ int lcnt[NBUCK], lloc[NBUCK], lbase[NBUCK];
    __shared__ int scan[1024];
    __shared__ uint32_t srec[PCHUNK];     // 64 KB
    int tid = threadIdx.x;
    if (blockIdx.x < NPART) {
        if (blockIdx.x == 0) {
            if (tid < NBUCK) atomicExch(&ctrl[tid], 0);
            __syncthreads();
            if (tid == 0) { __threadfence(); atomicExch(&ctrl[NBUCK], 1); }
        }
        if (tid < NBUCK) lcnt[tid] = 0;
        __syncthreads();
        int e0 = blockIdx.x * PCHUNK;
        int e1 = min(e0 + PCHUNK, N_EDGES);
        // pass 1: per-bucket counts (second read of this 128 KB chunk is L2-hot)
        for (int e = e0 + tid; e < e1; e += 1024)
            atomicAdd(&lcnt[dsts[e] >> 7], 1);
        __syncthreads();
        // block-wide exclusive scan of 782 counts (Hillis-Steele, 1024 thr)
        int v = (tid < NBUCK) ? lcnt[tid] : 0;
        scan[tid] = v;
        __syncthreads();
        for (int off = 1; off < 1024; off <<= 1) {
            int t = (tid >= off) ? scan[tid - off] : 0;
            __syncthreads();
            scan[tid] += t;
            __syncthreads();
        }
        if (tid < NBUCK) lloc[tid] = scan[tid] - v;
        // wait for cursor zeroing, then one reservation per nonzero bucket
        if (tid == 0)
            while (atomicAdd(&ctrl[NBUCK], 0) != 1) {}
        __syncthreads();
        if (tid < NBUCK) {
            lbase[tid] = v ? atomicAdd(&ctrl[tid], v) : 0;
            lcnt[tid] = 0;                // reuse as rank counter
        }
        __syncthreads();
        // pass 2: sort records into LDS by bucket
        for (int e = e0 + tid; e < e1; e += 1024) {
            int src = srcs[e];
            int dst = dsts[e];
            int b = dst >> 7;
            int r = atomicAdd(&lcnt[b], 1);
            srec[lloc[b] + r] = ((uint32_t)(dst & 127) << 24) | (uint32_t)src;
        }
        __syncthreads();
        // copy-out: contiguous ~21-record (84 B) runs, one bucket per wave-iter
        int wv = tid >> 6, ln = tid & 63;
        for (int b = wv; b < NBUCK; b += 16) {
            int c = lcnt[b];
            int lo = lloc[b], go = lbase[b];
            for (int j = ln; j < c; j += 64) {
                int pos = go + j;
                if (pos < CAPB)           // 17-sigma guard, never taken
                    pairs[(size_t)b * CAPB + pos] = srec[lo + j];
            }
        }
        return;
    }
    // ---- scores: 16 lanes per node, float4 per lane, 256 nodes per block ----
    int u0 = blockIdx.x - NPART;
    int g16 = tid >> 4;                   // 64 node-groups per iteration
    int ql = tid & 15;
    float4 wi4 = ((const float4*)w_i)[ql];
    float4 wj4 = ((const float4*)w_j)[ql];
#pragma unroll
    for (int i = 0; i < 4; ++i) {
        int node = u0 * 256 + i * 64 + g16;
        if (node >= N_NODES) break;
        float4 v = ((const float4*)x)[node * 16 + ql];
        float a = v.x * wi4.x + v.y * wi4.y + v.z * wi4.z + v.w * wi4.w;
        float b = v.x * wj4.x + v.y * wj4.y + v.z * wj4.z + v.w * wj4.w;
#pragma unroll
        for (int off = 1; off < 16; off <<= 1) {
            a += __shfl_xor(a, off, 64);
            b += __shfl_xor(b, off, 64);
        }
        if (ql == 0) { s_i[node] = a; s_j[node] = b; }
        ushort4 o;
        o.x = f2bf(v.x); o.y = f2bf(v.y); o.z = f2bf(v.z); o.w = f2bf(v.w);
        ((ushort4*)xb)[node * 16 + ql] = o;
    }
}

// bf16-pair unpack helpers
__device__ __forceinline__ float bflo(uint32_t d) { return __uint_as_float(d << 16); }
__device__ __forceinline__ float bfhi(uint32_t d) { return __uint_as_float(d & 0xFFFF0000u); }

// K2: ONE BLOCK PER FULL 128-NODE BUCKET, 1024 threads. LDS 51.2 KB ->
//     2 blocks/CU x 16 waves = 32 waves/CU. Staging keeps every record.
//     Gather: QUARTER-PER-NODE — each 16-lane quarter owns one node (lane
//     ql covers dims 4ql..4ql+3), 4 independent dep-chains per wave and 16
//     gathers in flight (vs 4 in the old 4-edges-of-one-node batch). No
//     cross-lane reduce needed: acc[4] per lane IS the output fragment and
//     den is quarter-replicated. Wave's 4 nodes are consecutive -> 1 KB
//     fully-coalesced output stores. Masked slots (count < wave-max) load
//     row 0 with w=0 (L1-hot, no OOB).
__global__ void __launch_bounds__(1024, 8) k_bucket_agg(const uint2* __restrict__ xw2,
                                                        const uint32_t* __restrict__ pairs,
                                                        const int* __restrict__ ctrl,
                                                        const float* __restrict__ s_i,
                                                        const float* __restrict__ s_j,
                                                        float* __restrict__ out) {
    __shared__ uint64_t spairs[128 * NCAP];   // 50.2 KB
    __shared__ int lcur[128];
    __shared__ float s_si[128];
    int tid = threadIdx.x;
    int cb = blockIdx.x;                  // one 128-node bucket per block
    int node0 = cb * 128;
    const uint32_t* reg = pairs + (size_t)cb * CAPB;
    int rcnt = min(ctrl[cb], CAPB);
    if (tid < 128) {
        lcur[tid] = 0;
        int node = node0 + tid;
        s_si[tid] = (node < N_NODES) ? s_i[node] : 0.f;
    }
    __syncthreads();
    // staging pass: EVERY record kept — compute w, direct-scatter to its node
    for (int e = tid; e < rcnt; e += 1024) {
        uint32_t p = reg[e];
        int n = (int)(p >> 24);           // dstl 0..127
        int src = (int)(p & 0xFFFFFFu);
        float sc = s_si[n] + s_j[src];
        sc = (sc > 0.f) ? sc : SLOPE * sc;
        float w = __expf(sc);
        int slot = atomicAdd(&lcur[n], 1);
        if (slot < NCAP)
            spairs[n * NCAP + slot] =
                ((uint64_t)__float_as_uint(w) << 32) | (uint32_t)src;
    }
    __syncthreads();
    int wave = tid >> 6, lane = tid & 63;
    int quarter = lane >> 4, ql = lane & 15;
    for (int half = 0; half < 2; ++half) {
        int k = wave * 4 + quarter + 64 * half;   // quarter's node, 0..127
        int node = node0 + k;
        int creal = lcur[k];
        int cq = min(creal, NCAP);
        // wave-wide max count across the 4 quarters (uniform loop bound)
        int mx = cq;
        mx = max(mx, __shfl_xor(mx, 16, 64));
        mx = max(mx, __shfl_xor(mx, 32, 64));
        const uint64_t* pp = spairs + k * NCAP;
        float acc0 = 0.f, acc1 = 0.f, acc2 = 0.f, acc3 = 0.f, den = 0.f;
        for (int j = 0; j < mx; j += 4) {
            uint64_t qv[4];
#pragma unroll
            for (int u = 0; u < 4; ++u) {
                int idx = j + u;
                qv[u] = pp[(idx < cq) ? idx : 0];
            }
            uint2 d[4];
            float wv[4];
#pragma unroll
            for (int u = 0; u < 4; ++u) {
                int idx = j + u;
                uint32_t src = (idx < cq) ? ((uint32_t)qv[u] & 0xFFFFFFu) : 0u;
                wv[u] = (idx < cq) ? __uint_as_float((uint32_t)(qv[u] >> 32)) : 0.f;
                d[u] = xw2[src * 16 + ql];
            }
#pragma unroll
            for (int u = 0; u < 4; ++u) {
                float w = wv[u];
                den += w;
                acc0 = fmaf(w, bflo(d[u].x), acc0);
                acc1 = fmaf(w, bfhi(d[u].x), acc1);
                acc2 = fmaf(w, bflo(d[u].y), acc2);
                acc3 = fmaf(w, bfhi(d[u].y), acc3);
            }
        }
        if (creal > NCAP) {
            // per-node overflow fallback (statistically unreachable)
            acc0 = acc1 = acc2 = acc3 = 0.f; den = 0.f;
            for (int e = 0; e < rcnt; ++e) {
                uint32_t p = reg[e];
                if ((int)(p >> 24) == k) {
                    int src = (int)(p & 0xFFFFFFu);
                    float sc = s_si[k] + s_j[src];
                    sc = (sc > 0.f) ? sc : SLOPE * sc;
                    float w = __expf(sc);
                    uint2 dd = xw2[(uint32_t)src * 16 + ql];
                    den += w;
                    acc0 = fmaf(w, bflo(dd.x), acc0);
                    acc1 = fmaf(w, bfhi(dd.x), acc1);
                    acc2 = fmaf(w, bflo(dd.y), acc2);
                    acc3 = fmaf(w, bfhi(dd.y), acc3);
                }
            }
        }
        if (node < N_NODES) {
            float4 r = make_float4(0.f, 0.f, 0.f, 0.f);
            if (creal > 0) {
                float inv = 1.f / den;
                r.x = fmaxf(acc0 * inv, 0.f);
                r.y = fmaxf(acc1 * inv, 0.f);
                r.z = fmaxf(acc2 * inv, 0.f);
                r.w = fmaxf(acc3 * inv, 0.f);
            }
            ((float4*)(out + (size_t)node * HIDDEN))[ql] = r;
        }
    }
}

extern "C" void kernel_launch(void* const* d_in, const int* in_sizes, int n_in,
                              void* d_out, int out_size, void* d_ws, size_t ws_size,
                              hipStream_t stream) {
    const float* x   = (const float*)d_in[0];
    const int*   ei  = (const int*)d_in[1];   // [2, E]: row0 = src (ej), row1 = dst (ei)
    const float* w_i = (const float*)d_in[2];
    const float* w_j = (const float*)d_in[3];
    float* out = (float*)d_out;

    char* p = (char*)d_ws;
    float*          s_i   = (float*)p;          p += (size_t)N_NODES * 4;
    float*          s_j   = (float*)p;          p += (size_t)N_NODES * 4;
    unsigned short* xb    = (unsigned short*)p; p += (size_t)N_NODES * HIDDEN * 2;
    int*            ctrl  = (int*)p;            p += 4096;
    uint32_t*       pairs = (uint32_t*)p;       // NBUCK * CAPB * 4 B = 8.8 MB

    const int* srcs = ei;             // edge_index[0]
    const int* dsts = ei + N_EDGES;   // edge_index[1]

    k_build     <<<NPART + NSB, 1024, 0, stream>>>(x, w_i, w_j, srcs, dsts,
                                                   s_i, s_j, xb, ctrl, pairs);
    k_bucket_agg<<<NBUCK, 1024, 0, stream>>>((const uint2*)xb, pairs, ctrl,
                                             s_i, s_j, out);
}

// Round 2
// 143.209 us; speedup vs baseline: 1.0586x; 1.0143x over previous
//
#include <hip/hip_runtime.h>
#include <stdint.h>

#define N_NODES 100000
#define N_EDGES 1600000
#define HIDDEN  64
#define SLOPE   0.01f
#define NBUCK   782      // ceil(N_NODES/128): coarse buckets of 128 dst nodes
#define CAPB    2816     // fixed slots per bucket (mean 2048, sd 45 -> 17 sigma)
#define PCHUNK  16384    // edges per partition block (98 blocks x 16 waves)
#define NPART   98       // ceil(N_EDGES/PCHUNK)
#define NSB     391      // scores blocks, 256 nodes each (391*256 = 100096)
#define NCAP    48       // per-node slot capacity (deg ~ Poisson(16); P(>48) ~ 3e-10)
#define NSTRIDE 50       // LDS record stride per node: 400 B -> (100 words % 32 = 4)
                         // de-banks the 4 quarters' ds_read_b64 (48*8B aliased to bank 0)

// ctrl layout: [0..NBUCK) bucket cursors; [NBUCK] init flag

// round-to-nearest-even fp32 -> bf16 (as ushort)
__device__ __forceinline__ unsigned short f2bf(float f) {
    uint32_t u = __float_as_uint(f);
    uint32_t r = u + 0x7FFFu + ((u >> 16) & 1u);
    return (unsigned short)(r >> 16);
}

// K1: fused build, 1024-thread blocks, ALL co-resident (489 blocks x 16
//     waves; 79 KB LDS -> 2 blocks/CU): build time ~ max(partition, scores).
//     Blocks [0, NPART): LDS-sort one 16384-edge chunk by bucket, reserve
//     once per (block,bucket), copy out as contiguous runs. Blocks
//     [NPART, NPART+NSB): scores + bf16 x copy, float4 per lane.
__global__ void __launch_bounds__(1024) k_build(const float* __restrict__ x,
                                                const float* __restrict__ w_i,
                                                const float* __restrict__ w_j,
                                                const int* __restrict__ srcs,
                                                const int* __restrict__ dsts,
                                                float* __restrict__ s_i,
                                                float* __restrict__ s_j,
                                                unsigned short* __restrict__ xb,
                                                int* __restrict__ ctrl,
                                                uint32_t* __restrict__ pairs) {
    __shared__ int lcnt[NBUCK], lloc[NBUCK], lbase[NBUCK];
    __shared__ int scan[1024];
    __shared__ uint32_t srec[PCHUNK];     // 64 KB
    int tid = threadIdx.x;
    if (blockIdx.x < NPART) {
        if (blockIdx.x == 0) {
            if (tid < NBUCK) atomicExch(&ctrl[tid], 0);
            __syncthreads();
            if (tid == 0) { __threadfence(); atomicExch(&ctrl[NBUCK], 1); }
        }
        if (tid < NBUCK) lcnt[tid] = 0;
        __syncthreads();
        int e0 = blockIdx.x * PCHUNK;
        int e1 = min(e0 + PCHUNK, N_EDGES);
        // pass 1: per-bucket counts (second read of this 128 KB chunk is L2-hot)
        for (int e = e0 + tid; e < e1; e += 1024)
            atomicAdd(&lcnt[dsts[e] >> 7], 1);
        __syncthreads();
        // block-wide exclusive scan of 782 counts (Hillis-Steele, 1024 thr)
        int v = (tid < NBUCK) ? lcnt[tid] : 0;
        scan[tid] = v;
        __syncthreads();
        for (int off = 1; off < 1024; off <<= 1) {
            int t = (tid >= off) ? scan[tid - off] : 0;
            __syncthreads();
            scan[tid] += t;
            __syncthreads();
        }
        if (tid < NBUCK) lloc[tid] = scan[tid] - v;
        // wait for cursor zeroing, then one reservation per nonzero bucket
        if (tid == 0)
            while (atomicAdd(&ctrl[NBUCK], 0) != 1) {}
        __syncthreads();
        if (tid < NBUCK) {
            lbase[tid] = v ? atomicAdd(&ctrl[tid], v) : 0;
            lcnt[tid] = 0;                // reuse as rank counter
        }
        __syncthreads();
        // pass 2: sort records into LDS by bucket
        for (int e = e0 + tid; e < e1; e += 1024) {
            int src = srcs[e];
            int dst = dsts[e];
            int b = dst >> 7;
            int r = atomicAdd(&lcnt[b], 1);
            srec[lloc[b] + r] = ((uint32_t)(dst & 127) << 24) | (uint32_t)src;
        }
        __syncthreads();
        // copy-out: contiguous ~21-record (84 B) runs, one bucket per wave-iter
        int wv = tid >> 6, ln = tid & 63;
        for (int b = wv; b < NBUCK; b += 16) {
            int c = lcnt[b];
            int lo = lloc[b], go = lbase[b];
            for (int j = ln; j < c; j += 64) {
                int pos = go + j;
                if (pos < CAPB)           // 17-sigma guard, never taken
                    pairs[(size_t)b * CAPB + pos] = srec[lo + j];
            }
        }
        return;
    }
    // ---- scores: 16 lanes per node, float4 per lane, 256 nodes per block ----
    int u0 = blockIdx.x - NPART;
    int g16 = tid >> 4;                   // 64 node-groups per iteration
    int ql = tid & 15;
    float4 wi4 = ((const float4*)w_i)[ql];
    float4 wj4 = ((const float4*)w_j)[ql];
#pragma unroll
    for (int i = 0; i < 4; ++i) {
        int node = u0 * 256 + i * 64 + g16;
        if (node >= N_NODES) break;
        float4 v = ((const float4*)x)[node * 16 + ql];
        float a = v.x * wi4.x + v.y * wi4.y + v.z * wi4.z + v.w * wi4.w;
        float b = v.x * wj4.x + v.y * wj4.y + v.z * wj4.z + v.w * wj4.w;
#pragma unroll
        for (int off = 1; off < 16; off <<= 1) {
            a += __shfl_xor(a, off, 64);
            b += __shfl_xor(b, off, 64);
        }
        if (ql == 0) { s_i[node] = a; s_j[node] = b; }
        ushort4 o;
        o.x = f2bf(v.x); o.y = f2bf(v.y); o.z = f2bf(v.z); o.w = f2bf(v.w);
        ((ushort4*)xb)[node * 16 + ql] = o;
    }
}

// bf16-pair unpack helpers
__device__ __forceinline__ float bflo(uint32_t d) { return __uint_as_float(d << 16); }
__device__ __forceinline__ float bfhi(uint32_t d) { return __uint_as_float(d & 0xFFFF0000u); }

// K2: one block per 128-node bucket, 1024 threads, 2 blocks/CU (wave-capped).
//     R2 changes — all aimed at EXPOSED LATENCY:
//     * spairs zero-filled -> padded slots read (w=0,src=0): no per-slot masks.
//     * staging manually 2-batched: both pairs loads then both s_j gathers in
//       flight (runtime-bound loop blocked compiler pipelining).
//     * gather: quarter-per-node, 8 lanes x uint4 per row -> ONE load instr
//       covers TWO slots (lanes 0-7 slot j, 8-15 slot j+1); 4 loads in flight
//       = 64 B/lane (was 32 B) and half the load/ds_read instructions; final
//       shfl_xor(8) folds the two slot-parities.
//     * node stride 50 records (400 B): quarters land on distinct LDS banks.
__global__ void __launch_bounds__(1024, 8) k_bucket_agg(const uint4* __restrict__ xw4,
                                                        const uint32_t* __restrict__ pairs,
                                                        const int* __restrict__ ctrl,
                                                        const float* __restrict__ s_i,
                                                        const float* __restrict__ s_j,
                                                        float* __restrict__ out) {
    __shared__ uint64_t spairs[128 * NSTRIDE];   // 51.2 KB
    __shared__ int lcur[128];
    __shared__ float s_si[128];
    int tid = threadIdx.x;
    int cb = blockIdx.x;                  // one 128-node bucket per block
    int node0 = cb * 128;
    const uint32_t* reg = pairs + (size_t)cb * CAPB;
    int rcnt = min(ctrl[cb], CAPB);
    // zero-fill record slots: padded reads contribute w=0 with src=0 (row 0 L1-hot)
    for (int i = tid; i < 128 * NSTRIDE; i += 1024) spairs[i] = 0ull;
    if (tid < 128) {
        lcur[tid] = 0;
        int node = node0 + tid;
        s_si[tid] = (node < N_NODES) ? s_i[node] : 0.f;
    }
    __syncthreads();
    // staging: 2-deep batched (rcnt mean 2048, sd 45); residual loop rare
    {
        int e0 = tid, e1 = tid + 1024;
        bool a0 = e0 < rcnt, a1 = e1 < rcnt;
        uint32_t p0 = a0 ? reg[e0] : 0u;
        uint32_t p1 = a1 ? reg[e1] : 0u;
        float sj0 = a0 ? s_j[p0 & 0xFFFFFFu] : 0.f;
        float sj1 = a1 ? s_j[p1 & 0xFFFFFFu] : 0.f;
        if (a0) {
            int n = (int)(p0 >> 24);
            float sc = s_si[n] + sj0;
            sc = (sc > 0.f) ? sc : SLOPE * sc;
            float w = __expf(sc);
            int slot = atomicAdd(&lcur[n], 1);
            if (slot < NCAP)
                spairs[n * NSTRIDE + slot] =
                    ((uint64_t)__float_as_uint(w) << 32) | (p0 & 0xFFFFFFu);
        }
        if (a1) {
            int n = (int)(p1 >> 24);
            float sc = s_si[n] + sj1;
            sc = (sc > 0.f) ? sc : SLOPE * sc;
            float w = __expf(sc);
            int slot = atomicAdd(&lcur[n], 1);
            if (slot < NCAP)
                spairs[n * NSTRIDE + slot] =
                    ((uint64_t)__float_as_uint(w) << 32) | (p1 & 0xFFFFFFu);
        }
        for (int e = tid + 2048; e < rcnt; e += 1024) {
            uint32_t p = reg[e];
            int n = (int)(p >> 24);
            float sc = s_si[n] + s_j[p & 0xFFFFFFu];
            sc = (sc > 0.f) ? sc : SLOPE * sc;
            float w = __expf(sc);
            int slot = atomicAdd(&lcur[n], 1);
            if (slot < NCAP)
                spairs[n * NSTRIDE + slot] =
                    ((uint64_t)__float_as_uint(w) << 32) | (p & 0xFFFFFFu);
        }
    }
    __syncthreads();
    int wave = tid >> 6, lane = tid & 63;
    int quarter = (lane >> 4) & 3;        // node within wave's group of 4
    int half8 = (lane >> 3) & 1;          // slot parity owned by this lane-octet
    int l8 = lane & 7;                    // 16 B chunk (8 dims) within row
    for (int hl = 0; hl < 2; ++hl) {
        int k = wave * 4 + quarter + 64 * hl;     // quarter's node, 0..127
        int node = node0 + k;
        int creal = lcur[k];
        int cq = min(creal, NCAP);
        // wave-wide max count across the 4 quarters (uniform loop bound)
        int mx = cq;
        mx = max(mx, __shfl_xor(mx, 16, 64));
        mx = max(mx, __shfl_xor(mx, 32, 64));
        const uint64_t* pp = spairs + k * NSTRIDE;
        float acc[8] = {0.f, 0.f, 0.f, 0.f, 0.f, 0.f, 0.f, 0.f};
        float den = 0.f;
        for (int j = 0; j < mx; j += 8) {         // 8 slots/iter, max access j+7 < 48
            uint64_t rec[4];
            uint4 d[4];
#pragma unroll
            for (int t = 0; t < 4; ++t)
                rec[t] = pp[j + 2 * t + half8];
#pragma unroll
            for (int t = 0; t < 4; ++t)
                d[t] = xw4[((uint32_t)rec[t] & 0xFFFFFFu) * 8 + l8];
#pragma unroll
            for (int t = 0; t < 4; ++t) {
                float w = __uint_as_float((uint32_t)(rec[t] >> 32));
                den += w;
                acc[0] = fmaf(w, bflo(d[t].x), acc[0]);
                acc[1] = fmaf(w, bfhi(d[t].x), acc[1]);
                acc[2] = fmaf(w, bflo(d[t].y), acc[2]);
                acc[3] = fmaf(w, bfhi(d[t].y), acc[3]);
                acc[4] = fmaf(w, bflo(d[t].z), acc[4]);
                acc[5] = fmaf(w, bfhi(d[t].z), acc[5]);
                acc[6] = fmaf(w, bflo(d[t].w), acc[6]);
                acc[7] = fmaf(w, bfhi(d[t].w), acc[7]);
            }
        }
        if (creal > NCAP) {
            // per-node overflow fallback (statistically unreachable)
#pragma unroll
            for (int i = 0; i < 8; ++i) acc[i] = 0.f;
            den = 0.f;
            for (int e = 0; e < rcnt; ++e) {
                uint32_t p = reg[e];
                if ((int)(p >> 24) == k) {
                    uint32_t src = p & 0xFFFFFFu;
                    float sc = s_si[k] + s_j[src];
                    sc = (sc > 0.f) ? sc : SLOPE * sc;
                    float w = (half8 == 0) ? __expf(sc) : 0.f;
                    uint4 dd = xw4[src * 8 + l8];
                    den += w;
                    acc[0] = fmaf(w, bflo(dd.x), acc[0]);
                    acc[1] = fmaf(w, bfhi(dd.x), acc[1]);
                    acc[2] = fmaf(w, bflo(dd.y), acc[2]);
                    acc[3] = fmaf(w, bfhi(dd.y), acc[3]);
                    acc[4] = fmaf(w, bflo(dd.z), acc[4]);
                    acc[5] = fmaf(w, bfhi(dd.z), acc[5]);
                    acc[6] = fmaf(w, bflo(dd.w), acc[6]);
                    acc[7] = fmaf(w, bfhi(dd.w), acc[7]);
                }
            }
        }
        // fold the two slot-parities (lane i <-> lane i+8)
#pragma unroll
        for (int i = 0; i < 8; ++i) acc[i] += __shfl_xor(acc[i], 8, 64);
        den += __shfl_xor(den, 8, 64);
        if (half8 == 0 && node < N_NODES) {
            float4 r0 = make_float4(0.f, 0.f, 0.f, 0.f);
            float4 r1 = r0;
            if (creal > 0) {
                float inv = 1.f / den;
                r0.x = fmaxf(acc[0] * inv, 0.f);
                r0.y = fmaxf(acc[1] * inv, 0.f);
                r0.z = fmaxf(acc[2] * inv, 0.f);
                r0.w = fmaxf(acc[3] * inv, 0.f);
                r1.x = fmaxf(acc[4] * inv, 0.f);
                r1.y = fmaxf(acc[5] * inv, 0.f);
                r1.z = fmaxf(acc[6] * inv, 0.f);
                r1.w = fmaxf(acc[7] * inv, 0.f);
            }
            float4* op = (float4*)(out + (size_t)node * HIDDEN + l8 * 8);
            op[0] = r0;
            op[1] = r1;
        }
    }
}

extern "C" void kernel_launch(void* const* d_in, const int* in_sizes, int n_in,
                              void* d_out, int out_size, void* d_ws, size_t ws_size,
                              hipStream_t stream) {
    const float* x   = (const float*)d_in[0];
    const int*   ei  = (const int*)d_in[1];   // [2, E]: row0 = src (ej), row1 = dst (ei)
    const float* w_i = (const float*)d_in[2];
    const float* w_j = (const float*)d_in[3];
    float* out = (float*)d_out;

    char* p = (char*)d_ws;
    float*          s_i   = (float*)p;          p += (size_t)N_NODES * 4;
    float*          s_j   = (float*)p;          p += (size_t)N_NODES * 4;
    unsigned short* xb    = (unsigned short*)p; p += (size_t)N_NODES * HIDDEN * 2;
    int*            ctrl  = (int*)p;            p += 4096;
    uint32_t*       pairs = (uint32_t*)p;       // NBUCK * CAPB * 4 B = 8.8 MB

    const int* srcs = ei;             // edge_index[0]
    const int* dsts = ei + N_EDGES;   // edge_index[1]

    k_build     <<<NPART + NSB, 1024, 0, stream>>>(x, w_i, w_j, srcs, dsts,
                                                   s_i, s_j, xb, ctrl, pairs);
    k_bucket_agg<<<NBUCK, 1024, 0, stream>>>((const uint4*)xb, pairs, ctrl,
                                             s_i, s_j, out);
}